// Round 8
// baseline (1292.987 us; speedup 1.0000x reference)
//
#include <hip/hip_runtime.h>

#define B 8
#define C 21
#define H 256
#define W 256
#define HW 65536
#define D 64
#define NPIX (B*HW)
#define EPSF 1e-8f
#define FG_CH 4      // pixel-range chunks per (b,d) row in k_fgsum

__device__ __forceinline__ unsigned enc_max(float v) {
    unsigned u = __float_as_uint(v);
    return (v >= 0.f) ? (u | 0x80000000u) : ~u;
}
__device__ __forceinline__ float dec_max(unsigned k) {
    return (k & 0x80000000u) ? __uint_as_float(k & 0x7fffffffu) : __uint_as_float(~k);
}

// ---------------- zero all accumulators once ----------------
__global__ void k_zero(double* fg_sum, double* st1, double* st2, unsigned* stm,
                       int* cnt0, int* cnt1, double* pooled_acc) {
    int tid = threadIdx.x;
    for (int i = tid; i < B * C * D; i += 256) fg_sum[i] = 0.0;
    if (tid < B * C) {
        st1[tid] = 0.0; st2[tid] = 0.0; stm[tid] = 0u;
        cnt0[tid] = 0; cnt1[tid] = 0; pooled_acc[tid] = 0.0;
    }
}

// ---- feat/normed/refined init + pooled accum + fgbits0 + fg_cnt0 ----
// 4 px/thread; two-pass over d (recompute) so feat[64] is never held live.
__global__ __launch_bounds__(256, 4)
void k_feat(const float* __restrict__ cam_raw,
            const float* __restrict__ proj_w,
            const float* __restrict__ proj_b,
            float* __restrict__ normed,
            float* __restrict__ refined,
            unsigned* __restrict__ fb0,
            int* __restrict__ cnt0,
            double* __restrict__ pooled_acc) {
    __shared__ float pw[D * C];
    __shared__ float pb[D];
    __shared__ double wp[4][C];
    __shared__ int wc[4][C];
    for (int i = threadIdx.x; i < D * C; i += 256) pw[i] = proj_w[i];
    if (threadIdx.x < D) pb[threadIdx.x] = proj_b[threadIdx.x];
    __syncthreads();
    int gid = blockIdx.x * 256 + threadIdx.x;       // 0..131071 (NPIX/4)
    int b = gid >> 14;
    int pix4 = (gid << 2) & 65535;
    int lane = threadIdx.x & 63, wv = threadIdx.x >> 6;
    float4 cam[C];
    unsigned m0 = 0, m1 = 0, m2 = 0, m3 = 0;
    #pragma unroll
    for (int c = 0; c < C; ++c) {
        float4 v = *reinterpret_cast<const float4*>(cam_raw + ((size_t)(b * C + c)) * HW + pix4);
        v.x = v.x > 0.f ? v.x : 0.f;
        v.y = v.y > 0.f ? v.y : 0.f;
        v.z = v.z > 0.f ? v.z : 0.f;
        v.w = v.w > 0.f ? v.w : 0.f;
        cam[c] = v;
        unsigned b0 = v.x > 0.1f ? 1u : 0u, b1 = v.y > 0.1f ? 1u : 0u;
        unsigned b2 = v.z > 0.1f ? 1u : 0u, b3 = v.w > 0.1f ? 1u : 0u;
        m0 |= b0 << c; m1 |= b1 << c; m2 |= b2 << c; m3 |= b3 << c;
        float4 r = make_float4((float)b0, (float)b1, (float)b2, (float)b3);
        *reinterpret_cast<float4*>(refined + ((size_t)(b * C + c)) * HW + pix4) = r;
    }
    *reinterpret_cast<uint4*>(fb0 + (size_t)b * HW + pix4) = make_uint4(m0, m1, m2, m3);
    // pass 1: squared norms
    float sx = 0.f, sy = 0.f, sz = 0.f, sw = 0.f;
    for (int d = 0; d < D; ++d) {
        float fx = pb[d], fy = fx, fz = fx, fw = fx;
        #pragma unroll
        for (int c = 0; c < C; ++c) {
            float ww = pw[d * C + c];
            fx = fmaf(ww, cam[c].x, fx);
            fy = fmaf(ww, cam[c].y, fy);
            fz = fmaf(ww, cam[c].z, fz);
            fw = fmaf(ww, cam[c].w, fw);
        }
        sx = fmaf(fx, fx, sx); sy = fmaf(fy, fy, sy);
        sz = fmaf(fz, fz, sz); sw = fmaf(fw, fw, sw);
    }
    float ix = 1.f / (sqrtf(sx) + EPSF);
    float iy = 1.f / (sqrtf(sy) + EPSF);
    float iz = 1.f / (sqrtf(sz) + EPSF);
    float iw = 1.f / (sqrtf(sw) + EPSF);
    // pass 2: recompute + normalized store
    for (int d = 0; d < D; ++d) {
        float fx = pb[d], fy = fx, fz = fx, fw = fx;
        #pragma unroll
        for (int c = 0; c < C; ++c) {
            float ww = pw[d * C + c];
            fx = fmaf(ww, cam[c].x, fx);
            fy = fmaf(ww, cam[c].y, fy);
            fz = fmaf(ww, cam[c].z, fz);
            fw = fmaf(ww, cam[c].w, fw);
        }
        float4 o = make_float4(fx * ix, fy * iy, fz * iz, fw * iw);
        *reinterpret_cast<float4*>(normed + ((size_t)(b * D + d)) * HW + pix4) = o;
    }
    // fg counts (per-thread 0..4 per class, butterfly int sum)
    #pragma unroll
    for (int c = 0; c < C; ++c) {
        int v = (int)((m0 >> c) & 1u) + (int)((m1 >> c) & 1u)
              + (int)((m2 >> c) & 1u) + (int)((m3 >> c) & 1u);
        #pragma unroll
        for (int o = 32; o > 0; o >>= 1) v += __shfl_xor(v, o);
        if (lane == 0) wc[wv][c] = v;
    }
    // pooled partial (f64 butterfly)
    #pragma unroll
    for (int c = 0; c < C; ++c) {
        double s = (double)cam[c].x + (double)cam[c].y + (double)cam[c].z + (double)cam[c].w;
        #pragma unroll
        for (int o = 32; o > 0; o >>= 1) s += __shfl_xor(s, o);
        if (lane == 0) wp[wv][c] = s;
    }
    __syncthreads();
    if (threadIdx.x < C) {
        int c = threadIdx.x;
        atomicAdd(&cnt0[b * C + c], wc[0][c] + wc[1][c] + wc[2][c] + wc[3][c]);
        atomicAdd(&pooled_acc[b * C + c], wp[0][c] + wp[1][c] + wp[2][c] + wp[3][c]);
    }
}

// ---- masked feature sums: fg_sum[b,c,d] += normed[b,d,p] where mask bit set ----
__global__ __launch_bounds__(256, 4)
void k_fgsum(const float* __restrict__ normed,
             const unsigned* __restrict__ fb,
             double* __restrict__ fg_sum) {
    int bd = blockIdx.y;
    int b = bd >> 6, d = bd & 63;
    int seg = blockIdx.x;
    const float* nf = normed + ((size_t)(b * D + d)) * HW + seg * (HW / FG_CH);
    const unsigned* mb = fb + (size_t)b * HW + seg * (HW / FG_CH);
    float acc[C];
    #pragma unroll
    for (int c = 0; c < C; ++c) acc[c] = 0.f;
    for (int p = 0; p < HW / FG_CH; p += 1024) {
        int off = p + threadIdx.x * 4;
        float4 v = *reinterpret_cast<const float4*>(nf + off);
        uint4 m = *reinterpret_cast<const uint4*>(mb + off);
        #pragma unroll
        for (int c = 0; c < C; ++c) {
            acc[c] = fmaf((float)((m.x >> c) & 1u), v.x, acc[c]);
            acc[c] = fmaf((float)((m.y >> c) & 1u), v.y, acc[c]);
            acc[c] = fmaf((float)((m.z >> c) & 1u), v.z, acc[c]);
            acc[c] = fmaf((float)((m.w >> c) & 1u), v.w, acc[c]);
        }
    }
    int lane = threadIdx.x & 63;
    #pragma unroll
    for (int c = 0; c < C; ++c) {
        double s = (double)acc[c];
        #pragma unroll
        for (int o = 32; o > 0; o >>= 1) s += __shfl_xor(s, o);
        if (lane == 0) atomicAdd(&fg_sum[((size_t)(b * C + c)) * D + d], s);
    }
}

// ---- sim = normed . fg_mean (4 px/thread) + fused fg_mean prologue + stats ----
__global__ __launch_bounds__(256, 2)
void k_sim(const float* __restrict__ normed,
           const double* __restrict__ fg_sum,
           const int* __restrict__ cnt,
           float* __restrict__ sim,
           double* __restrict__ st1, double* __restrict__ st2,
           unsigned* __restrict__ stm,
           const double* __restrict__ pooled_acc,
           float* __restrict__ pooled, int first) {
    int b = blockIdx.y;
    __shared__ float fm[C * D];
    __shared__ double w1[4][C], w2[4][C];
    __shared__ float wm[4][C];
    for (int i = threadIdx.x; i < C * D; i += 256) {
        int c = i / D;
        fm[i] = (float)(fg_sum[(size_t)b * C * D + i] / ((double)cnt[b * C + c] + 1e-8));
    }
    if (first && blockIdx.x == 0 && threadIdx.x < B * C)
        pooled[threadIdx.x] = (float)(pooled_acc[threadIdx.x] / 65536.0);
    __syncthreads();
    int pix4 = (blockIdx.x * 256 + threadIdx.x) * 4;
    int lane = threadIdx.x & 63, wv = threadIdx.x >> 6;
    const float* nb = normed + (size_t)b * D * HW + pix4;
    float4 acc[C];
    #pragma unroll
    for (int c = 0; c < C; ++c) acc[c] = make_float4(0.f, 0.f, 0.f, 0.f);
    for (int d0 = 0; d0 < D; d0 += 4) {
        float4 v0 = *reinterpret_cast<const float4*>(nb + (size_t)(d0 + 0) * HW);
        float4 v1 = *reinterpret_cast<const float4*>(nb + (size_t)(d0 + 1) * HW);
        float4 v2 = *reinterpret_cast<const float4*>(nb + (size_t)(d0 + 2) * HW);
        float4 v3 = *reinterpret_cast<const float4*>(nb + (size_t)(d0 + 3) * HW);
        #pragma unroll
        for (int c = 0; c < C; ++c) {
            float4 f = *reinterpret_cast<const float4*>(&fm[c * D + d0]);
            acc[c].x = fmaf(v0.x, f.x, acc[c].x); acc[c].y = fmaf(v0.y, f.x, acc[c].y);
            acc[c].z = fmaf(v0.z, f.x, acc[c].z); acc[c].w = fmaf(v0.w, f.x, acc[c].w);
            acc[c].x = fmaf(v1.x, f.y, acc[c].x); acc[c].y = fmaf(v1.y, f.y, acc[c].y);
            acc[c].z = fmaf(v1.z, f.y, acc[c].z); acc[c].w = fmaf(v1.w, f.y, acc[c].w);
            acc[c].x = fmaf(v2.x, f.z, acc[c].x); acc[c].y = fmaf(v2.y, f.z, acc[c].y);
            acc[c].z = fmaf(v2.z, f.z, acc[c].z); acc[c].w = fmaf(v2.w, f.z, acc[c].w);
            acc[c].x = fmaf(v3.x, f.w, acc[c].x); acc[c].y = fmaf(v3.y, f.w, acc[c].y);
            acc[c].z = fmaf(v3.z, f.w, acc[c].z); acc[c].w = fmaf(v3.w, f.w, acc[c].w);
        }
    }
    #pragma unroll
    for (int c = 0; c < C; ++c)
        *reinterpret_cast<float4*>(sim + ((size_t)(b * C + c)) * HW + pix4) = acc[c];
    // fused stats
    #pragma unroll
    for (int c = 0; c < C; ++c) {
        double x = acc[c].x, y = acc[c].y, z = acc[c].z, w = acc[c].w;
        double s1 = x + y + z + w;
        double s2 = x * x + y * y + z * z + w * w;
        float mx = fmaxf(fmaxf(acc[c].x, acc[c].y), fmaxf(acc[c].z, acc[c].w));
        #pragma unroll
        for (int o = 32; o > 0; o >>= 1) {
            s1 += __shfl_xor(s1, o);
            s2 += __shfl_xor(s2, o);
            mx = fmaxf(mx, __shfl_xor(mx, o));
        }
        if (lane == 0) { w1[wv][c] = s1; w2[wv][c] = s2; wm[wv][c] = mx; }
    }
    __syncthreads();
    if (threadIdx.x < C) {
        int c = threadIdx.x;
        double s1 = w1[0][c] + w1[1][c] + w1[2][c] + w1[3][c];
        double s2 = w2[0][c] + w2[1][c] + w2[2][c] + w2[3][c];
        float mx = fmaxf(fmaxf(wm[0][c], wm[1][c]), fmaxf(wm[2][c], wm[3][c]));
        atomicAdd(&st1[b * C + c], s1);
        atomicAdd(&st2[b * C + c], s2);
        atomicMax(&stm[b * C + c], enc_max(mx));
    }
}

// ---- thr/den/act from stats; zero next-iteration accumulators (8 blocks) ----
__global__ void k_thr(double* __restrict__ st1, double* __restrict__ st2,
                      unsigned* __restrict__ stm,
                      const int* __restrict__ cnt_cur, const int* __restrict__ labels,
                      float* __restrict__ thr_arr, float* __restrict__ den_arr,
                      float* __restrict__ act_arr, float strict,
                      double* __restrict__ fg_sum, int* __restrict__ cnt_nxt) {
    const int slice = B * C * D / 8;
    int base = blockIdx.x * slice;
    for (int i = threadIdx.x; i < slice; i += 256) fg_sum[base + i] = 0.0;
    if (blockIdx.x == 0) {
        int bc = threadIdx.x;
        if (bc < B * C) {
            double n = 65536.0;
            double s1 = st1[bc], s2 = st2[bc];
            double mean = s1 / n;
            double var = (s2 - s1 * s1 / n) / (n - 1.0);
            if (var < 0.0) var = 0.0;
            float t = (float)(mean + (double)strict * sqrt(var));
            float mx = dec_max(stm[bc]);
            thr_arr[bc] = t;
            den_arr[bc] = mx - t + EPSF;
            act_arr[bc] = (cnt_cur[bc] > 0 && labels[bc] > 0) ? 1.f : 0.f;
            st1[bc] = 0.0; st2[bc] = 0.0; stm[bc] = 0u; cnt_nxt[bc] = 0;
        }
    }
}

// ---- refined update (4 px/thread) + next fgbits + next fg_cnt ----
__global__ void k_update(const float* __restrict__ sim,
                         const unsigned* __restrict__ fbc,
                         unsigned* __restrict__ fbn,
                         const float* __restrict__ thr_arr, const float* __restrict__ den_arr,
                         const float* __restrict__ act_arr,
                         float* __restrict__ refined, int* __restrict__ cnt_nxt, int it) {
    int b = blockIdx.y;
    int t = blockIdx.x * 256 + threadIdx.x;    // 0..16383
    int pix4 = t * 4;
    int h = pix4 >> 8, w = pix4 & 255;
    int lane = threadIdx.x & 63, wv = threadIdx.x >> 6;
    const unsigned* fb = fbc + (size_t)b * HW;
    uint4 msv = *reinterpret_cast<const uint4*>(fb + pix4);
    unsigned ms[4] = {msv.x, msv.y, msv.z, msv.w};
    unsigned dil[4];
    if (it > 0) {
        unsigned up[6], mi[6], dn[6];
        bool hm = h > 0, hp = h < H - 1;
        #pragma unroll
        for (int j = 0; j < 6; ++j) {
            int ww = w - 1 + j;
            bool okw = (ww >= 0) && (ww < W);
            mi[j] = okw ? fb[h * W + ww] : 0u;
            up[j] = (okw && hm) ? fb[(h - 1) * W + ww] : 0u;
            dn[j] = (okw && hp) ? fb[(h + 1) * W + ww] : 0u;
        }
        #pragma unroll
        for (int j = 0; j < 4; ++j)
            dil[j] = up[j] | up[j+1] | up[j+2] | mi[j] | mi[j+1] | mi[j+2]
                   | dn[j] | dn[j+1] | dn[j+2];
    } else {
        #pragma unroll
        for (int j = 0; j < 4; ++j) dil[j] = 0xFFFFFFFFu;
    }
    unsigned nm[4] = {0u, 0u, 0u, 0u};
    int cnt[C];
    #pragma unroll
    for (int c = 0; c < C; ++c) cnt[c] = 0;
    #pragma unroll
    for (int c = 0; c < C; ++c) {
        int bc = b * C + c;
        float thr = thr_arr[bc], den = den_arr[bc], act = act_arr[bc];
        size_t idx = (size_t)bc * HW + pix4;
        float4 s4 = *reinterpret_cast<const float4*>(sim + idx);
        float4 r4 = *reinterpret_cast<float4*>(refined + idx);
        float sv[4] = {s4.x, s4.y, s4.z, s4.w};
        float rv[4] = {r4.x, r4.y, r4.z, r4.w};
        bool changed = false;
        #pragma unroll
        for (int j = 0; j < 4; ++j) {
            bool fg = (ms[j] >> c) & 1u;
            bool npx = (sv[j] > thr) && !fg && ((dil[j] >> c) & 1u);
            if (npx && act > 0.f) {
                float conf = (sv[j] - thr) / den;
                conf = fminf(fmaxf(conf, 0.1f), 0.9f);
                rv[j] += conf;
                changed = true;
            }
            unsigned nb = (rv[j] > 0.5f) ? 1u : 0u;
            nm[j] |= nb << c;
            cnt[c] += (int)nb;
        }
        if (changed) {
            float4 o4 = make_float4(rv[0], rv[1], rv[2], rv[3]);
            *reinterpret_cast<float4*>(refined + idx) = o4;
        }
    }
    uint4 nmv = make_uint4(nm[0], nm[1], nm[2], nm[3]);
    *reinterpret_cast<uint4*>(fbn + (size_t)b * HW + pix4) = nmv;
    // reduce counts
    __shared__ int wc[4][C];
    #pragma unroll
    for (int c = 0; c < C; ++c) {
        int v = cnt[c];
        #pragma unroll
        for (int o = 32; o > 0; o >>= 1) v += __shfl_xor(v, o);
        if (lane == 0) wc[wv][c] = v;
    }
    __syncthreads();
    if (threadIdx.x < C) {
        int c = threadIdx.x;
        atomicAdd(&cnt_nxt[b * C + c], wc[0][c] + wc[1][c] + wc[2][c] + wc[3][c]);
    }
}

// ---- clip + first-argmax one-hot, 4 px/thread ----
__global__ __launch_bounds__(256, 2)
void k_final(float* __restrict__ refined) {
    int b = blockIdx.y;
    int pix4 = (blockIdx.x * 256 + threadIdx.x) * 4;
    float4 vals[C];
    #pragma unroll
    for (int c = 0; c < C; ++c) {
        float4 v = *reinterpret_cast<const float4*>(refined + ((size_t)(b * C + c)) * HW + pix4);
        v.x = fminf(fmaxf(v.x, 0.f), 1.f);
        v.y = fminf(fmaxf(v.y, 0.f), 1.f);
        v.z = fminf(fmaxf(v.z, 0.f), 1.f);
        v.w = fminf(fmaxf(v.w, 0.f), 1.f);
        vals[c] = v;
    }
    int bi[4] = {0, 0, 0, 0};
    float bv[4] = {vals[0].x, vals[0].y, vals[0].z, vals[0].w};
    #pragma unroll
    for (int c = 1; c < C; ++c) {
        float vv[4] = {vals[c].x, vals[c].y, vals[c].z, vals[c].w};
        #pragma unroll
        for (int j = 0; j < 4; ++j)
            if (vv[j] > bv[j]) { bv[j] = vv[j]; bi[j] = c; }
    }
    #pragma unroll
    for (int c = 0; c < C; ++c) {
        float4 v = vals[c];
        float4 o;
        o.x = (bi[0] == c) ? v.x : 0.f;
        o.y = (bi[1] == c) ? v.y : 0.f;
        o.z = (bi[2] == c) ? v.z : 0.f;
        o.w = (bi[3] == c) ? v.w : 0.f;
        *reinterpret_cast<float4*>(refined + ((size_t)(b * C + c)) * HW + pix4) = o;
    }
}

extern "C" void kernel_launch(void* const* d_in, const int* in_sizes, int n_in,
                              void* d_out, int out_size, void* d_ws, size_t ws_size,
                              hipStream_t stream) {
    const float* cam_raw = (const float*)d_in[0];
    const float* proj_w  = (const float*)d_in[1];
    const float* proj_b  = (const float*)d_in[2];
    const int*   labels  = (const int*)d_in[3];
    float* out = (float*)d_out;
    float* pooled  = out;            // [B,C]
    float* refined = out + B * C;    // [B,C,HW]

    char* ws = (char*)d_ws;
    float* normed = (float*)ws;          ws += (size_t)B * D * HW * 4;
    float* sim    = (float*)ws;          ws += (size_t)B * C * HW * 4;
    unsigned* fb0 = (unsigned*)ws;       ws += (size_t)B * HW * 4;
    unsigned* fb1 = (unsigned*)ws;       ws += (size_t)B * HW * 4;
    double* fg_sum = (double*)ws;        ws += (size_t)B * C * D * 8;
    double* st1    = (double*)ws;        ws += (size_t)B * C * 8;
    double* st2    = (double*)ws;        ws += (size_t)B * C * 8;
    double* pooled_acc = (double*)ws;    ws += (size_t)B * C * 8;
    unsigned* stm  = (unsigned*)ws;      ws += (size_t)B * C * 4;
    int* cnt0      = (int*)ws;           ws += (size_t)B * C * 4;
    int* cnt1      = (int*)ws;           ws += (size_t)B * C * 4;
    float* thr_arr = (float*)ws;         ws += (size_t)B * C * 4;
    float* den_arr = (float*)ws;         ws += (size_t)B * C * 4;
    float* act_arr = (float*)ws;         ws += (size_t)B * C * 4;
    unsigned* fbs[2] = {fb0, fb1};
    int* cnts[2] = {cnt0, cnt1};

    hipLaunchKernelGGL(k_zero, dim3(1), dim3(256), 0, stream,
                       fg_sum, st1, st2, stm, cnt0, cnt1, pooled_acc);
    hipLaunchKernelGGL(k_feat, dim3(NPIX / 1024), dim3(256), 0, stream,
                       cam_raw, proj_w, proj_b, normed, refined, fb0, cnt0, pooled_acc);
    for (int it = 0; it < 5; ++it) {
        int cur = it & 1, nxt = cur ^ 1;
        hipLaunchKernelGGL(k_fgsum, dim3(FG_CH, B * D), dim3(256), 0, stream,
                           normed, fbs[cur], fg_sum);
        hipLaunchKernelGGL(k_sim, dim3(HW / 1024, B), dim3(256), 0, stream,
                           normed, fg_sum, cnts[cur], sim, st1, st2, stm,
                           pooled_acc, pooled, it == 0 ? 1 : 0);
        float strict = (float)(0.5 - 0.05 * (double)it);
        hipLaunchKernelGGL(k_thr, dim3(8), dim3(256), 0, stream,
                           st1, st2, stm, cnts[cur], labels,
                           thr_arr, den_arr, act_arr, strict, fg_sum, cnts[nxt]);
        hipLaunchKernelGGL(k_update, dim3(HW / 1024, B), dim3(256), 0, stream,
                           sim, fbs[cur], fbs[nxt], thr_arr, den_arr, act_arr,
                           refined, cnts[nxt], it);
    }
    hipLaunchKernelGGL(k_final, dim3(HW / 1024, B), dim3(256), 0, stream, refined);
}

// Round 9
// 928.496 us; speedup vs baseline: 1.3926x; 1.3926x over previous
//
#include <hip/hip_runtime.h>

#define B 8
#define C 21
#define H 256
#define W 256
#define HW 65536
#define D 64
#define NPIX (B*HW)
#define EPSF 1e-8f
#define FG_CH 4      // pixel-range chunks per (b,d) row in k_fgsum

__device__ __forceinline__ unsigned enc_max(float v) {
    unsigned u = __float_as_uint(v);
    return (v >= 0.f) ? (u | 0x80000000u) : ~u;
}
__device__ __forceinline__ float dec_max(unsigned k) {
    return (k & 0x80000000u) ? __uint_as_float(k & 0x7fffffffu) : __uint_as_float(~k);
}

// ---------------- zero all accumulators once ----------------
__global__ void k_zero(double* fg_sum, double* st1, double* st2, unsigned* stm,
                       int* cnt0, int* cnt1, double* pooled_acc) {
    int tid = threadIdx.x;
    for (int i = tid; i < B * C * D; i += 256) fg_sum[i] = 0.0;
    if (tid < B * C) {
        st1[tid] = 0.0; st2[tid] = 0.0; stm[tid] = 0u;
        cnt0[tid] = 0; cnt1[tid] = 0; pooled_acc[tid] = 0.0;
    }
}

// ---- feat/normed/refined init + pooled accum + fgbits0 + fg_cnt0 ----
// ROUND-1 measured-good structure (1 px/thread, VGPR 56, 112us), with ONE
// change: 64 divides -> 1 reciprocal + 64 multiplies.
__global__ __launch_bounds__(256, 2)
void k_feat(const float* __restrict__ cam_raw,
            const float* __restrict__ proj_w,
            const float* __restrict__ proj_b,
            float* __restrict__ normed,
            float* __restrict__ refined,
            unsigned* __restrict__ fb0,
            int* __restrict__ cnt0,
            double* __restrict__ pooled_acc) {
    __shared__ float pw[D * C];
    __shared__ float pb[D];
    __shared__ double wp[4][C];
    __shared__ int wc[4][C];
    for (int i = threadIdx.x; i < D * C; i += 256) pw[i] = proj_w[i];
    if (threadIdx.x < D) pb[threadIdx.x] = proj_b[threadIdx.x];
    __syncthreads();
    int gid = blockIdx.x * 256 + threadIdx.x;
    int b = gid >> 16, pix = gid & 65535;
    int lane = threadIdx.x & 63, wv = threadIdx.x >> 6;
    float cam[C];
    unsigned m = 0;
    #pragma unroll
    for (int c = 0; c < C; ++c) {
        float v = cam_raw[((size_t)(b * C + c)) * HW + pix];
        v = v > 0.f ? v : 0.f;
        cam[c] = v;
        refined[((size_t)(b * C + c)) * HW + pix] = (v > 0.1f) ? 1.f : 0.f;
        m |= (v > 0.1f ? 1u : 0u) << c;
    }
    fb0[(size_t)b * HW + pix] = m;
    float feat[D];
    float ss = 0.f;
    #pragma unroll
    for (int d = 0; d < D; ++d) {
        float f = pb[d];
        #pragma unroll
        for (int c = 0; c < C; ++c) f = fmaf(pw[d * C + c], cam[c], f);
        feat[d] = f;
        ss = fmaf(f, f, ss);
    }
    float inv = 1.f / (sqrtf(ss) + EPSF);
    #pragma unroll
    for (int d = 0; d < D; ++d)
        normed[((size_t)(b * D + d)) * HW + pix] = feat[d] * inv;
    // fg counts via ballot
    #pragma unroll
    for (int c = 0; c < C; ++c) {
        unsigned long long bl = __ballot((m >> c) & 1u);
        if (lane == 0) wc[wv][c] = (int)__popcll(bl);
    }
    // pooled partial (f64 butterfly)
    #pragma unroll
    for (int c = 0; c < C; ++c) {
        double s = (double)cam[c];
        #pragma unroll
        for (int o = 32; o > 0; o >>= 1) s += __shfl_xor(s, o);
        if (lane == 0) wp[wv][c] = s;
    }
    __syncthreads();
    if (threadIdx.x < C) {
        int c = threadIdx.x;
        atomicAdd(&cnt0[b * C + c], wc[0][c] + wc[1][c] + wc[2][c] + wc[3][c]);
        atomicAdd(&pooled_acc[b * C + c], wp[0][c] + wp[1][c] + wp[2][c] + wp[3][c]);
    }
}

// ---- masked feature sums: fg_sum[b,c,d] += normed[b,d,p] where mask bit set ----
__global__ __launch_bounds__(256, 4)
void k_fgsum(const float* __restrict__ normed,
             const unsigned* __restrict__ fb,
             double* __restrict__ fg_sum) {
    int bd = blockIdx.y;
    int b = bd >> 6, d = bd & 63;
    int seg = blockIdx.x;
    const float* nf = normed + ((size_t)(b * D + d)) * HW + seg * (HW / FG_CH);
    const unsigned* mb = fb + (size_t)b * HW + seg * (HW / FG_CH);
    float acc[C];
    #pragma unroll
    for (int c = 0; c < C; ++c) acc[c] = 0.f;
    for (int p = 0; p < HW / FG_CH; p += 1024) {
        int off = p + threadIdx.x * 4;
        float4 v = *reinterpret_cast<const float4*>(nf + off);
        uint4 m = *reinterpret_cast<const uint4*>(mb + off);
        #pragma unroll
        for (int c = 0; c < C; ++c) {
            acc[c] = fmaf((float)((m.x >> c) & 1u), v.x, acc[c]);
            acc[c] = fmaf((float)((m.y >> c) & 1u), v.y, acc[c]);
            acc[c] = fmaf((float)((m.z >> c) & 1u), v.z, acc[c]);
            acc[c] = fmaf((float)((m.w >> c) & 1u), v.w, acc[c]);
        }
    }
    int lane = threadIdx.x & 63;
    #pragma unroll
    for (int c = 0; c < C; ++c) {
        double s = (double)acc[c];
        #pragma unroll
        for (int o = 32; o > 0; o >>= 1) s += __shfl_xor(s, o);
        if (lane == 0) atomicAdd(&fg_sum[((size_t)(b * C + c)) * D + d], s);
    }
}

// ---- sim = normed . fg_mean (4 px/thread) + fused fg_mean prologue + stats ----
__global__ __launch_bounds__(256, 2)
void k_sim(const float* __restrict__ normed,
           const double* __restrict__ fg_sum,
           const int* __restrict__ cnt,
           float* __restrict__ sim,
           double* __restrict__ st1, double* __restrict__ st2,
           unsigned* __restrict__ stm,
           const double* __restrict__ pooled_acc,
           float* __restrict__ pooled, int first) {
    int b = blockIdx.y;
    __shared__ float fm[C * D];
    __shared__ double w1[4][C], w2[4][C];
    __shared__ float wm[4][C];
    for (int i = threadIdx.x; i < C * D; i += 256) {
        int c = i / D;
        fm[i] = (float)(fg_sum[(size_t)b * C * D + i] / ((double)cnt[b * C + c] + 1e-8));
    }
    if (first && blockIdx.x == 0 && threadIdx.x < B * C)
        pooled[threadIdx.x] = (float)(pooled_acc[threadIdx.x] / 65536.0);
    __syncthreads();
    int pix4 = (blockIdx.x * 256 + threadIdx.x) * 4;
    int lane = threadIdx.x & 63, wv = threadIdx.x >> 6;
    const float* nb = normed + (size_t)b * D * HW + pix4;
    float4 acc[C];
    #pragma unroll
    for (int c = 0; c < C; ++c) acc[c] = make_float4(0.f, 0.f, 0.f, 0.f);
    for (int d0 = 0; d0 < D; d0 += 4) {
        float4 v0 = *reinterpret_cast<const float4*>(nb + (size_t)(d0 + 0) * HW);
        float4 v1 = *reinterpret_cast<const float4*>(nb + (size_t)(d0 + 1) * HW);
        float4 v2 = *reinterpret_cast<const float4*>(nb + (size_t)(d0 + 2) * HW);
        float4 v3 = *reinterpret_cast<const float4*>(nb + (size_t)(d0 + 3) * HW);
        #pragma unroll
        for (int c = 0; c < C; ++c) {
            float4 f = *reinterpret_cast<const float4*>(&fm[c * D + d0]);
            acc[c].x = fmaf(v0.x, f.x, acc[c].x); acc[c].y = fmaf(v0.y, f.x, acc[c].y);
            acc[c].z = fmaf(v0.z, f.x, acc[c].z); acc[c].w = fmaf(v0.w, f.x, acc[c].w);
            acc[c].x = fmaf(v1.x, f.y, acc[c].x); acc[c].y = fmaf(v1.y, f.y, acc[c].y);
            acc[c].z = fmaf(v1.z, f.y, acc[c].z); acc[c].w = fmaf(v1.w, f.y, acc[c].w);
            acc[c].x = fmaf(v2.x, f.z, acc[c].x); acc[c].y = fmaf(v2.y, f.z, acc[c].y);
            acc[c].z = fmaf(v2.z, f.z, acc[c].z); acc[c].w = fmaf(v2.w, f.z, acc[c].w);
            acc[c].x = fmaf(v3.x, f.w, acc[c].x); acc[c].y = fmaf(v3.y, f.w, acc[c].y);
            acc[c].z = fmaf(v3.z, f.w, acc[c].z); acc[c].w = fmaf(v3.w, f.w, acc[c].w);
        }
    }
    #pragma unroll
    for (int c = 0; c < C; ++c)
        *reinterpret_cast<float4*>(sim + ((size_t)(b * C + c)) * HW + pix4) = acc[c];
    // fused stats
    #pragma unroll
    for (int c = 0; c < C; ++c) {
        double x = acc[c].x, y = acc[c].y, z = acc[c].z, w = acc[c].w;
        double s1 = x + y + z + w;
        double s2 = x * x + y * y + z * z + w * w;
        float mx = fmaxf(fmaxf(acc[c].x, acc[c].y), fmaxf(acc[c].z, acc[c].w));
        #pragma unroll
        for (int o = 32; o > 0; o >>= 1) {
            s1 += __shfl_xor(s1, o);
            s2 += __shfl_xor(s2, o);
            mx = fmaxf(mx, __shfl_xor(mx, o));
        }
        if (lane == 0) { w1[wv][c] = s1; w2[wv][c] = s2; wm[wv][c] = mx; }
    }
    __syncthreads();
    if (threadIdx.x < C) {
        int c = threadIdx.x;
        double s1 = w1[0][c] + w1[1][c] + w1[2][c] + w1[3][c];
        double s2 = w2[0][c] + w2[1][c] + w2[2][c] + w2[3][c];
        float mx = fmaxf(fmaxf(wm[0][c], wm[1][c]), fmaxf(wm[2][c], wm[3][c]));
        atomicAdd(&st1[b * C + c], s1);
        atomicAdd(&st2[b * C + c], s2);
        atomicMax(&stm[b * C + c], enc_max(mx));
    }
}

// ---- thr/den/act from stats; zero next-iteration accumulators (8 blocks) ----
__global__ void k_thr(double* __restrict__ st1, double* __restrict__ st2,
                      unsigned* __restrict__ stm,
                      const int* __restrict__ cnt_cur, const int* __restrict__ labels,
                      float* __restrict__ thr_arr, float* __restrict__ den_arr,
                      float* __restrict__ act_arr, float strict,
                      double* __restrict__ fg_sum, int* __restrict__ cnt_nxt) {
    const int slice = B * C * D / 8;
    int base = blockIdx.x * slice;
    for (int i = threadIdx.x; i < slice; i += 256) fg_sum[base + i] = 0.0;
    if (blockIdx.x == 0) {
        int bc = threadIdx.x;
        if (bc < B * C) {
            double n = 65536.0;
            double s1 = st1[bc], s2 = st2[bc];
            double mean = s1 / n;
            double var = (s2 - s1 * s1 / n) / (n - 1.0);
            if (var < 0.0) var = 0.0;
            float t = (float)(mean + (double)strict * sqrt(var));
            float mx = dec_max(stm[bc]);
            thr_arr[bc] = t;
            den_arr[bc] = mx - t + EPSF;
            act_arr[bc] = (cnt_cur[bc] > 0 && labels[bc] > 0) ? 1.f : 0.f;
            st1[bc] = 0.0; st2[bc] = 0.0; stm[bc] = 0u; cnt_nxt[bc] = 0;
        }
    }
}

// ---- refined update (4 px/thread) + next fgbits + next fg_cnt ----
__global__ void k_update(const float* __restrict__ sim,
                         const unsigned* __restrict__ fbc,
                         unsigned* __restrict__ fbn,
                         const float* __restrict__ thr_arr, const float* __restrict__ den_arr,
                         const float* __restrict__ act_arr,
                         float* __restrict__ refined, int* __restrict__ cnt_nxt, int it) {
    int b = blockIdx.y;
    int t = blockIdx.x * 256 + threadIdx.x;    // 0..16383
    int pix4 = t * 4;
    int h = pix4 >> 8, w = pix4 & 255;
    int lane = threadIdx.x & 63, wv = threadIdx.x >> 6;
    const unsigned* fb = fbc + (size_t)b * HW;
    uint4 msv = *reinterpret_cast<const uint4*>(fb + pix4);
    unsigned ms[4] = {msv.x, msv.y, msv.z, msv.w};
    unsigned dil[4];
    if (it > 0) {
        unsigned up[6], mi[6], dn[6];
        bool hm = h > 0, hp = h < H - 1;
        #pragma unroll
        for (int j = 0; j < 6; ++j) {
            int ww = w - 1 + j;
            bool okw = (ww >= 0) && (ww < W);
            mi[j] = okw ? fb[h * W + ww] : 0u;
            up[j] = (okw && hm) ? fb[(h - 1) * W + ww] : 0u;
            dn[j] = (okw && hp) ? fb[(h + 1) * W + ww] : 0u;
        }
        #pragma unroll
        for (int j = 0; j < 4; ++j)
            dil[j] = up[j] | up[j+1] | up[j+2] | mi[j] | mi[j+1] | mi[j+2]
                   | dn[j] | dn[j+1] | dn[j+2];
    } else {
        #pragma unroll
        for (int j = 0; j < 4; ++j) dil[j] = 0xFFFFFFFFu;
    }
    unsigned nm[4] = {0u, 0u, 0u, 0u};
    int cnt[C];
    #pragma unroll
    for (int c = 0; c < C; ++c) cnt[c] = 0;
    #pragma unroll
    for (int c = 0; c < C; ++c) {
        int bc = b * C + c;
        float thr = thr_arr[bc], den = den_arr[bc], act = act_arr[bc];
        size_t idx = (size_t)bc * HW + pix4;
        float4 s4 = *reinterpret_cast<const float4*>(sim + idx);
        float4 r4 = *reinterpret_cast<float4*>(refined + idx);
        float sv[4] = {s4.x, s4.y, s4.z, s4.w};
        float rv[4] = {r4.x, r4.y, r4.z, r4.w};
        bool changed = false;
        #pragma unroll
        for (int j = 0; j < 4; ++j) {
            bool fg = (ms[j] >> c) & 1u;
            bool npx = (sv[j] > thr) && !fg && ((dil[j] >> c) & 1u);
            if (npx && act > 0.f) {
                float conf = (sv[j] - thr) / den;
                conf = fminf(fmaxf(conf, 0.1f), 0.9f);
                rv[j] += conf;
                changed = true;
            }
            unsigned nb = (rv[j] > 0.5f) ? 1u : 0u;
            nm[j] |= nb << c;
            cnt[c] += (int)nb;
        }
        if (changed) {
            float4 o4 = make_float4(rv[0], rv[1], rv[2], rv[3]);
            *reinterpret_cast<float4*>(refined + idx) = o4;
        }
    }
    uint4 nmv = make_uint4(nm[0], nm[1], nm[2], nm[3]);
    *reinterpret_cast<uint4*>(fbn + (size_t)b * HW + pix4) = nmv;
    // reduce counts
    __shared__ int wc[4][C];
    #pragma unroll
    for (int c = 0; c < C; ++c) {
        int v = cnt[c];
        #pragma unroll
        for (int o = 32; o > 0; o >>= 1) v += __shfl_xor(v, o);
        if (lane == 0) wc[wv][c] = v;
    }
    __syncthreads();
    if (threadIdx.x < C) {
        int c = threadIdx.x;
        atomicAdd(&cnt_nxt[b * C + c], wc[0][c] + wc[1][c] + wc[2][c] + wc[3][c]);
    }
}

// ---- clip + first-argmax one-hot, 4 px/thread ----
__global__ __launch_bounds__(256, 2)
void k_final(float* __restrict__ refined) {
    int b = blockIdx.y;
    int pix4 = (blockIdx.x * 256 + threadIdx.x) * 4;
    float4 vals[C];
    #pragma unroll
    for (int c = 0; c < C; ++c) {
        float4 v = *reinterpret_cast<const float4*>(refined + ((size_t)(b * C + c)) * HW + pix4);
        v.x = fminf(fmaxf(v.x, 0.f), 1.f);
        v.y = fminf(fmaxf(v.y, 0.f), 1.f);
        v.z = fminf(fmaxf(v.z, 0.f), 1.f);
        v.w = fminf(fmaxf(v.w, 0.f), 1.f);
        vals[c] = v;
    }
    int bi[4] = {0, 0, 0, 0};
    float bv[4] = {vals[0].x, vals[0].y, vals[0].z, vals[0].w};
    #pragma unroll
    for (int c = 1; c < C; ++c) {
        float vv[4] = {vals[c].x, vals[c].y, vals[c].z, vals[c].w};
        #pragma unroll
        for (int j = 0; j < 4; ++j)
            if (vv[j] > bv[j]) { bv[j] = vv[j]; bi[j] = c; }
    }
    #pragma unroll
    for (int c = 0; c < C; ++c) {
        float4 v = vals[c];
        float4 o;
        o.x = (bi[0] == c) ? v.x : 0.f;
        o.y = (bi[1] == c) ? v.y : 0.f;
        o.z = (bi[2] == c) ? v.z : 0.f;
        o.w = (bi[3] == c) ? v.w : 0.f;
        *reinterpret_cast<float4*>(refined + ((size_t)(b * C + c)) * HW + pix4) = o;
    }
}

extern "C" void kernel_launch(void* const* d_in, const int* in_sizes, int n_in,
                              void* d_out, int out_size, void* d_ws, size_t ws_size,
                              hipStream_t stream) {
    const float* cam_raw = (const float*)d_in[0];
    const float* proj_w  = (const float*)d_in[1];
    const float* proj_b  = (const float*)d_in[2];
    const int*   labels  = (const int*)d_in[3];
    float* out = (float*)d_out;
    float* pooled  = out;            // [B,C]
    float* refined = out + B * C;    // [B,C,HW]

    char* ws = (char*)d_ws;
    float* normed = (float*)ws;          ws += (size_t)B * D * HW * 4;
    float* sim    = (float*)ws;          ws += (size_t)B * C * HW * 4;
    unsigned* fb0 = (unsigned*)ws;       ws += (size_t)B * HW * 4;
    unsigned* fb1 = (unsigned*)ws;       ws += (size_t)B * HW * 4;
    double* fg_sum = (double*)ws;        ws += (size_t)B * C * D * 8;
    double* st1    = (double*)ws;        ws += (size_t)B * C * 8;
    double* st2    = (double*)ws;        ws += (size_t)B * C * 8;
    double* pooled_acc = (double*)ws;    ws += (size_t)B * C * 8;
    unsigned* stm  = (unsigned*)ws;      ws += (size_t)B * C * 4;
    int* cnt0      = (int*)ws;           ws += (size_t)B * C * 4;
    int* cnt1      = (int*)ws;           ws += (size_t)B * C * 4;
    float* thr_arr = (float*)ws;         ws += (size_t)B * C * 4;
    float* den_arr = (float*)ws;         ws += (size_t)B * C * 4;
    float* act_arr = (float*)ws;         ws += (size_t)B * C * 4;
    unsigned* fbs[2] = {fb0, fb1};
    int* cnts[2] = {cnt0, cnt1};

    hipLaunchKernelGGL(k_zero, dim3(1), dim3(256), 0, stream,
                       fg_sum, st1, st2, stm, cnt0, cnt1, pooled_acc);
    hipLaunchKernelGGL(k_feat, dim3(NPIX / 256), dim3(256), 0, stream,
                       cam_raw, proj_w, proj_b, normed, refined, fb0, cnt0, pooled_acc);
    for (int it = 0; it < 5; ++it) {
        int cur = it & 1, nxt = cur ^ 1;
        hipLaunchKernelGGL(k_fgsum, dim3(FG_CH, B * D), dim3(256), 0, stream,
                           normed, fbs[cur], fg_sum);
        hipLaunchKernelGGL(k_sim, dim3(HW / 1024, B), dim3(256), 0, stream,
                           normed, fg_sum, cnts[cur], sim, st1, st2, stm,
                           pooled_acc, pooled, it == 0 ? 1 : 0);
        float strict = (float)(0.5 - 0.05 * (double)it);
        hipLaunchKernelGGL(k_thr, dim3(8), dim3(256), 0, stream,
                           st1, st2, stm, cnts[cur], labels,
                           thr_arr, den_arr, act_arr, strict, fg_sum, cnts[nxt]);
        hipLaunchKernelGGL(k_update, dim3(HW / 1024, B), dim3(256), 0, stream,
                           sim, fbs[cur], fbs[nxt], thr_arr, den_arr, act_arr,
                           refined, cnts[nxt], it);
    }
    hipLaunchKernelGGL(k_final, dim3(HW / 1024, B), dim3(256), 0, stream, refined);
}